// Round 1
// baseline (259.140 us; speedup 1.0000x reference)
//
#include <hip/hip_runtime.h>
#include <hip/hip_fp16.h>
#include <math.h>

#define NEG_SLOPE 0.2f
#define LOG2E 1.44269504088896f

#if __has_builtin(__builtin_amdgcn_exp2f)
#define EXP2(x) __builtin_amdgcn_exp2f(x)
#else
#define EXP2(x) exp2f(x)
#endif

typedef _Float16 half8 __attribute__((ext_vector_type(8)));
typedef float floatx4 __attribute__((ext_vector_type(4)));

// ---------------- L1: pack W1 (blocks 0..15) + zero deg (blocks 16..) --------------
__global__ __launch_bounds__(256) void prep1(const float* __restrict__ W1,
                                             half8* __restrict__ Bpack,
                                             int* __restrict__ deg, int N) {
  if (blockIdx.x < 16) {
    int tid = blockIdx.x * 256 + threadIdx.x;  // 4096 total
    int l = tid & 63;
    int ksnt = tid >> 6;
    int ks = ksnt & 3;
    int nt = ksnt >> 2;
    int col = nt * 16 + (l & 15);
    int krow = ks * 32 + (l >> 4) * 8;
    half8 v;
#pragma unroll
    for (int j = 0; j < 8; j++) v[j] = (_Float16)W1[(krow + j) * 256 + col];
    Bpack[tid] = v;
  } else {
    int i = (blockIdx.x - 16) * 256 + threadIdx.x;
    if (i < N) deg[i] = 0;
  }
}

// ---------------- L2: gemm1 MFMA -> int8 h1 (per-row scale) + att dots ∥ hist+rank --
__global__ __launch_bounds__(256) void phase2(
    const float* __restrict__ x, const half8* __restrict__ Bpack,
    const float* __restrict__ att_s, const float* __restrict__ att_d,
    unsigned char* __restrict__ h1q, float* __restrict__ hscale,
    float* __restrict__ a1s, float* __restrict__ a1d,
    const int* __restrict__ dst, int* __restrict__ deg, int* __restrict__ rank,
    int N, int E, int gemmBlocks, int histBlocks) {
  if ((int)blockIdx.x >= gemmBlocks) {
    int b = blockIdx.x - gemmBlocks;
    for (int e = b * 256 + threadIdx.x; e < E; e += histBlocks * 256)
      rank[e] = atomicAdd(deg + dst[e], 1);
    return;
  }
  const int wave = threadIdx.x >> 6, lane = threadIdx.x & 63;
  const int quad = lane >> 4, li = lane & 15;
  const int n0 = (blockIdx.x * 4 + wave) * 16;
  if (n0 >= N) return;
  floatx4 acc[16];
#pragma unroll
  for (int t = 0; t < 16; t++) acc[t] = (floatx4){0.f, 0.f, 0.f, 0.f};
  const float* xrow = x + (size_t)(n0 + li) * 128;
#pragma unroll
  for (int ks = 0; ks < 4; ks++) {
    float4 xa = *(const float4*)(xrow + ks * 32 + quad * 8);
    float4 xb = *(const float4*)(xrow + ks * 32 + quad * 8 + 4);
    half8 a;
    a[0] = (_Float16)xa.x; a[1] = (_Float16)xa.y;
    a[2] = (_Float16)xa.z; a[3] = (_Float16)xa.w;
    a[4] = (_Float16)xb.x; a[5] = (_Float16)xb.y;
    a[6] = (_Float16)xb.z; a[7] = (_Float16)xb.w;
#pragma unroll
    for (int nt = 0; nt < 16; nt++) {
      half8 b = Bpack[(nt * 4 + ks) * 64 + lane];
      acc[nt] = __builtin_amdgcn_mfma_f32_16x16x32_f16(a, b, acc[nt], 0, 0, 0);
    }
  }
  // int8 quantize: row (m = quad*4 + r) absmax over 256 ch -> scale
#pragma unroll
  for (int r = 0; r < 4; r++) {
    float m = 0.f;
#pragma unroll
    for (int nt = 0; nt < 16; nt++) m = fmaxf(m, fabsf(acc[nt][r]));
#pragma unroll
    for (int off = 8; off > 0; off >>= 1) m = fmaxf(m, __shfl_xor(m, off, 16));
    m = fmaxf(m, 1e-8f);
    float inv = 127.0f / m;
    int node = n0 + quad * 4 + r;
    if (li == 0) hscale[node] = m * (1.0f / 127.0f);
#pragma unroll
    for (int nt = 0; nt < 16; nt++) {
      h1q[(size_t)node * 256 + nt * 16 + li] =
          (unsigned char)(int)(fmaf(acc[nt][r], inv, 128.5f));
    }
  }
  // fused attention dots (fp32 acc, pre-quantization), pre-scaled by log2e
  float as_f[16], ad_f[16];
#pragma unroll
  for (int nt = 0; nt < 16; nt++) {
    as_f[nt] = att_s[nt * 16 + li];
    ad_f[nt] = att_d[nt * 16 + li];
  }
#pragma unroll
  for (int r = 0; r < 4; r++) {
    int node = n0 + quad * 4 + r;
#pragma unroll
    for (int h = 0; h < 4; h++) {
      float vs = 0.f, vd = 0.f;
#pragma unroll
      for (int ntl = 0; ntl < 4; ntl++) {
        int nt = h * 4 + ntl;
        vs = fmaf(acc[nt][r], as_f[nt], vs);
        vd = fmaf(acc[nt][r], ad_f[nt], vd);
      }
#pragma unroll
      for (int off = 8; off > 0; off >>= 1) {
        vs += __shfl_down(vs, off, 16);
        vd += __shfl_down(vd, off, 16);
      }
      if (li == 0) {
        a1s[node * 4 + h] = vs * LOG2E;
        a1d[node * 4 + h] = vd * LOG2E;
      }
    }
  }
}

// ---------------- CSR scan chain (unpadded rows) ----------------
__global__ void scan_local(const int* __restrict__ deg, int* __restrict__ excl,
                           int* __restrict__ bsum, int N) {
  __shared__ int s[256];
  int i = blockIdx.x * 256 + threadIdx.x;
  int v = (i < N) ? deg[i] + 1 : 0;  // +1 self-loop
  s[threadIdx.x] = v;
  __syncthreads();
  for (int off = 1; off < 256; off <<= 1) {
    int t = (threadIdx.x >= off) ? s[threadIdx.x - off] : 0;
    __syncthreads();
    s[threadIdx.x] += t;
    __syncthreads();
  }
  if (i < N) excl[i] = s[threadIdx.x] - v;
  if (threadIdx.x == 255) bsum[blockIdx.x] = s[255];
}

// scan_add2: every block re-scans bsum in LDS (nb <= 256), writes rowptr + self-loop
__global__ void scan_add2(const int* __restrict__ excl, const int* __restrict__ bsum,
                          int* __restrict__ rowptr, int* __restrict__ elist,
                          int N, int nb) {
  __shared__ int s[256];
  int v = (threadIdx.x < nb) ? bsum[threadIdx.x] : 0;
  s[threadIdx.x] = v;
  __syncthreads();
  for (int off = 1; off < 256; off <<= 1) {
    int t = (threadIdx.x >= off) ? s[threadIdx.x - off] : 0;
    __syncthreads();
    s[threadIdx.x] += t;
    __syncthreads();
  }
  __syncthreads();
  int base = (blockIdx.x > 0) ? s[blockIdx.x - 1] : 0;  // exclusive block offset
  int i = blockIdx.x * 256 + threadIdx.x;
  if (i < N) {
    int r = excl[i] + base;
    rowptr[i] = r;
    elist[r] = i;  // self-loop first
  }
  if (blockIdx.x == 0 && threadIdx.x == 0) rowptr[N] = s[nb - 1];  // total = ET
}

// ---------------- atomic-free scatter via precomputed rank ----------------
__global__ void scatter2(const int* __restrict__ src, const int* __restrict__ dst,
                         const int* __restrict__ rank, const int* __restrict__ rowptr,
                         int* __restrict__ elist, int E) {
  int e = blockIdx.x * 256 + threadIdx.x;
  if (e >= E) return;
  elist[rowptr[dst[e]] + 1 + rank[e]] = src[e];
}

// ---------------- agg1: restructured two-phase edge loop.
// Phase A (edge-parallel): lane i of a half-wave owns edge j+i. One coalesced el
// load fetches 32 edge ids; one float4 gather fetches all 4 heads' a1s; each lane
// computes exp2 for 4 heads of ITS edge (4 exp2/edge total vs 32 redundant) and
// accumulates den/T privately. Hand-off via wave-private LDS (ordered by
// lgkmcnt(0) + sched_barrier — no __syncthreads in the divergent loop).
// Phase B (channel-parallel): unroll-8 batched uint2 row gathers (8 rows in
// flight per half-wave), LDS-broadcast se/offset, proven cvt+fma MAC.
// __launch_bounds__(256,4): VGPR headroom (old kernel squeezed to 32 VGPRs and
// serialized every load round-trip). Epilogue (R10) unchanged. --------------------
__global__ __launch_bounds__(256, 4) void agg1_fused(
    const int* __restrict__ rowptr, const int* __restrict__ elist,
    const unsigned char* __restrict__ h1q, const float* __restrict__ hscale,
    const float* __restrict__ a1s, const float* __restrict__ a1d,
    const float* __restrict__ b1, const float* __restrict__ W2,
    const float* __restrict__ as2, const float* __restrict__ ad2,
    __half* __restrict__ h2, float* __restrict__ a2s, float* __restrict__ a2d,
    int N) {
  __shared__ float w2s[64 * 41];   // lane-stride 41 -> conflict-free
  __shared__ float cbuf[8][256];   // normalized pre-bias outputs of this block's nodes
  __shared__ float sem[8][32][4];  // per-slot: se[edge][head]
  __shared__ int soff[8][32];      // per-slot: src byte offset (s*256)
  const int t = threadIdx.x;
  for (int i = t; i < 2560; i += 256) {
    int ch = i / 10, jj = i - ch * 10;
    w2s[(ch >> 2) * 41 + (ch & 3) * 10 + jj] = W2[i];
  }

  const int wave = t >> 6, lane = t & 63;
  const int half = lane >> 5, l32 = lane & 31;
  const int slot = wave * 2 + half;        // node slot in block: 0..7
  const int n = blockIdx.x * 8 + slot;
  const bool act = n < N;
  const int row = act ? rowptr[n] : 0;
  const int deg = act ? rowptr[n + 1] - row : 0;
  const int* el = elist + row;
  const int hidx = l32 >> 3;               // head of this lane's 8 channels
  float4 adv = act ? *(const float4*)(a1d + (size_t)n * 4)
                   : make_float4(0.f, 0.f, 0.f, 0.f);

  const float* semp = &sem[slot][0][0];
  const int* sp = &soff[slot][0];
  const unsigned char* h1ql = h1q + l32 * 8;

  float den4[4] = {0.f, 0.f, 0.f, 0.f};
  float T4[4] = {0.f, 0.f, 0.f, 0.f};
  float acc[8];
#pragma unroll
  for (int k = 0; k < 8; k++) acc[k] = 0.f;

  for (int j = 0; j < deg; j += 32) {
    int m = deg - j;
    if (m > 32) m = 32;
    // ---- phase A: this lane owns edge j + l32 ----
    int idx = j + l32;
    bool valid = idx < deg;
    if (idx >= deg) idx = deg - 1;  // clamp: stay inside this row of elist
    int s = el[idx];
    float4 av = *(const float4*)(a1s + (size_t)s * 4);
    float sc = hscale[s];
    float4 sev;
    {
      float l0 = av.x + adv.x;
      float l1 = av.y + adv.y;
      float l2 = av.z + adv.z;
      float l3 = av.w + adv.w;
      float e0 = EXP2(fmaxf(l0, NEG_SLOPE * l0));
      float e1 = EXP2(fmaxf(l1, NEG_SLOPE * l1));
      float e2 = EXP2(fmaxf(l2, NEG_SLOPE * l2));
      float e3 = EXP2(fmaxf(l3, NEG_SLOPE * l3));
      e0 = valid ? e0 : 0.f;
      e1 = valid ? e1 : 0.f;
      e2 = valid ? e2 : 0.f;
      e3 = valid ? e3 : 0.f;
      den4[0] += e0; den4[1] += e1; den4[2] += e2; den4[3] += e3;
      sev.x = e0 * sc; sev.y = e1 * sc; sev.z = e2 * sc; sev.w = e3 * sc;
      T4[0] += sev.x; T4[1] += sev.y; T4[2] += sev.z; T4[3] += sev.w;
    }
    // WAR guard: make sure last round's phase-B ds_reads finished before overwrite
    __builtin_amdgcn_sched_barrier(0);
    asm volatile("s_waitcnt lgkmcnt(0)" ::: "memory");
    __builtin_amdgcn_sched_barrier(0);
    *(float4*)&sem[slot][l32][0] = sev;
    soff[slot][l32] = s << 8;  // precomputed byte offset into h1q
    // RAW guard: writes visible before reads (same wave, exec-masked safe)
    __builtin_amdgcn_sched_barrier(0);
    asm volatile("s_waitcnt lgkmcnt(0)" ::: "memory");
    __builtin_amdgcn_sched_barrier(0);
    // ---- phase B: channel-parallel MAC over the m staged edges ----
    int u = 0;
    for (; u + 8 <= m; u += 8) {
      int ov[8];
      float se[8];
      uint2 qv[8];
#pragma unroll
      for (int k = 0; k < 8; k++) {
        ov[k] = sp[u + k];
        se[k] = semp[(u + k) * 4 + hidx];
      }
#pragma unroll
      for (int k = 0; k < 8; k++)
        qv[k] = *(const uint2*)(h1ql + (size_t)(unsigned)ov[k]);
#pragma unroll
      for (int k = 0; k < 8; k++) {
        unsigned int a = qv[k].x, b = qv[k].y;
        float w = se[k];
        acc[0] = fmaf((float)(a & 0xffu), w, acc[0]);
        acc[1] = fmaf((float)((a >> 8) & 0xffu), w, acc[1]);
        acc[2] = fmaf((float)((a >> 16) & 0xffu), w, acc[2]);
        acc[3] = fmaf((float)(a >> 24), w, acc[3]);
        acc[4] = fmaf((float)(b & 0xffu), w, acc[4]);
        acc[5] = fmaf((float)((b >> 8) & 0xffu), w, acc[5]);
        acc[6] = fmaf((float)((b >> 16) & 0xffu), w, acc[6]);
        acc[7] = fmaf((float)(b >> 24), w, acc[7]);
      }
    }
    for (; u < m; u++) {
      int o0 = sp[u];
      float w = semp[u * 4 + hidx];
      uint2 q0 = *(const uint2*)(h1ql + (size_t)(unsigned)o0);
      unsigned int a = q0.x, b = q0.y;
      acc[0] = fmaf((float)(a & 0xffu), w, acc[0]);
      acc[1] = fmaf((float)((a >> 8) & 0xffu), w, acc[1]);
      acc[2] = fmaf((float)((a >> 16) & 0xffu), w, acc[2]);
      acc[3] = fmaf((float)(a >> 24), w, acc[3]);
      acc[4] = fmaf((float)(b & 0xffu), w, acc[4]);
      acc[5] = fmaf((float)((b >> 8) & 0xffu), w, acc[5]);
      acc[6] = fmaf((float)((b >> 16) & 0xffu), w, acc[6]);
      acc[7] = fmaf((float)(b >> 24), w, acc[7]);
    }
  }

  // reduce den/T across the 32 lanes of this half-wave (disjoint edge subsets)
#pragma unroll
  for (int off = 16; off > 0; off >>= 1) {
#pragma unroll
    for (int h = 0; h < 4; h++) {
      den4[h] += __shfl_xor(den4[h], off, 32);
      T4[h] += __shfl_xor(T4[h], off, 32);
    }
  }

  // normalized, offset-corrected, pre-bias values -> LDS
  if (act) {
    float inv = 1.0f / den4[hidx];
    float corr = 128.0f * T4[hidx];
    float4 v0 = make_float4((acc[0] - corr) * inv, (acc[1] - corr) * inv,
                            (acc[2] - corr) * inv, (acc[3] - corr) * inv);
    float4 v1 = make_float4((acc[4] - corr) * inv, (acc[5] - corr) * inv,
                            (acc[6] - corr) * inv, (acc[7] - corr) * inv);
    *(float4*)&cbuf[slot][l32 * 8] = v0;
    *(float4*)&cbuf[slot][l32 * 8 + 4] = v1;
  }
  __syncthreads();

  // epilogue (R10 layout): wave handles its 2 nodes sequentially, 4 ch/lane
  float4 bb = *(const float4*)(b1 + lane * 4);
  const float* w0 = w2s + lane * 41;
#pragma unroll
  for (int pp = 0; pp < 2; pp++) {
    int slot2 = wave * 2 + pp;
    int n2 = blockIdx.x * 8 + slot2;
    if (n2 >= N) continue;  // uniform per wave
    float4 cv = *(const float4*)&cbuf[slot2][lane * 4];
    float c0 = cv.x + bb.x;
    float c1 = cv.y + bb.y;
    float c2 = cv.z + bb.z;
    float c3 = cv.w + bb.w;
    c0 = c0 > 0.f ? c0 : expm1f(c0);
    c1 = c1 > 0.f ? c1 : expm1f(c1);
    c2 = c2 > 0.f ? c2 : expm1f(c2);
    c3 = c3 > 0.f ? c3 : expm1f(c3);
    float p[10];
#pragma unroll
    for (int jj = 0; jj < 10; jj++)
      p[jj] = fmaf(c0, w0[jj],
              fmaf(c1, w0[10 + jj], fmaf(c2, w0[20 + jj], c3 * w0[30 + jj])));
#pragma unroll
    for (int jj = 0; jj < 10; jj++) {
#pragma unroll
      for (int off = 32; off > 0; off >>= 1) p[jj] += __shfl_down(p[jj], off, 64);
    }
    if (lane == 0) {
      float ds = 0.f, dd = 0.f;
#pragma unroll
      for (int jj = 0; jj < 10; jj++) {
        h2[(size_t)n2 * 16 + jj] = __float2half(p[jj]);
        ds = fmaf(p[jj], as2[jj], ds);
        dd = fmaf(p[jj], ad2[jj], dd);
      }
      a2s[n2] = ds * LOG2E;
      a2d[n2] = dd * LOG2E;
    }
  }
}

// ---------------- agg2: wave-per-node, 12 groups x 5 lanes (half2 = 2 channels),
// unroll-2: 24 edge-slots per iteration, 5x less lane redundancy than R10 ----------
__global__ __launch_bounds__(256) void agg2_csr(
    const int* __restrict__ rowptr, const int* __restrict__ elist,
    const __half* __restrict__ h2, const float* __restrict__ a2s,
    const float* __restrict__ a2d, const float* __restrict__ b2,
    float* __restrict__ out, int N) {
  int wave = threadIdx.x >> 6, lane = threadIdx.x & 63;
  int n = blockIdx.x * 4 + wave;
  if (n >= N) return;
  int row = rowptr[n];
  int deg = rowptr[n + 1] - row;
  const int* el = elist + row;
  float ad = a2d[n];     // pre-scaled
  int g = lane / 5;      // 0..11 active, lanes 60-63 idle (g=12)
  int c2 = lane - g * 5; // channel-pair index 0..4
  float den = 0.f, ax = 0.f, ay = 0.f;
  if (g < 12) {
    int jj = g;
    for (; jj + 12 < deg; jj += 24) {
      int sA = el[jj], sB = el[jj + 12];
      float lA = a2s[sA] + ad;
      float lB = a2s[sB] + ad;
      __half2 hA = *(const __half2*)(h2 + (size_t)sA * 16 + c2 * 2);
      __half2 hB = *(const __half2*)(h2 + (size_t)sB * 16 + c2 * 2);
      float eA = EXP2(fmaxf(lA, NEG_SLOPE * lA));
      float eB = EXP2(fmaxf(lB, NEG_SLOPE * lB));
      den += eA + eB;
      float2 fA = __half22float2(hA);
      float2 fB = __half22float2(hB);
      ax = fmaf(eA, fA.x, fmaf(eB, fB.x, ax));
      ay = fmaf(eA, fA.y, fmaf(eB, fB.y, ay));
    }
    for (; jj < deg; jj += 12) {
      int s = el[jj];
      float l = a2s[s] + ad;
      __half2 hv = *(const __half2*)(h2 + (size_t)s * 16 + c2 * 2);
      float ev = EXP2(fmaxf(l, NEG_SLOPE * l));
      den += ev;
      float2 f = __half22float2(hv);
      ax = fmaf(ev, f.x, ax);
      ay = fmaf(ev, f.y, ay);
    }
  }
  // reduce the 12 stride-5 groups: +30 (g+6), then +10/+20 (g+2,g+4), then +5 (g+1)
  ax += __shfl_down(ax, 30, 64);
  ay += __shfl_down(ay, 30, 64);
  den += __shfl_down(den, 30, 64);
  ax += __shfl_down(ax, 10, 64) + __shfl_down(ax, 20, 64);
  ay += __shfl_down(ay, 10, 64) + __shfl_down(ay, 20, 64);
  den += __shfl_down(den, 10, 64) + __shfl_down(den, 20, 64);
  ax += __shfl_down(ax, 5, 64);
  ay += __shfl_down(ay, 5, 64);
  den += __shfl_down(den, 5, 64);
  if (lane < 5) {
    float inv = 1.0f / den;
    float2 bb = *(const float2*)(b2 + lane * 2);
    float2 o = make_float2(fmaf(ax, inv, bb.x), fmaf(ay, inv, bb.y));
    *(float2*)(out + (size_t)n * 10 + lane * 2) = o;
  }
}

extern "C" void kernel_launch(void* const* d_in, const int* in_sizes, int n_in,
                              void* d_out, int out_size, void* d_ws, size_t ws_size,
                              hipStream_t stream) {
  const float* x = (const float*)d_in[0];
  const int* ei = (const int*)d_in[1];
  const float* W1 = (const float*)d_in[2];
  const float* as1 = (const float*)d_in[3];
  const float* ad1 = (const float*)d_in[4];
  const float* b1 = (const float*)d_in[5];
  const float* W2 = (const float*)d_in[6];
  const float* as2 = (const float*)d_in[7];
  const float* ad2 = (const float*)d_in[8];
  const float* b2 = (const float*)d_in[9];
  float* out = (float*)d_out;

  const int N = in_sizes[0] / 128;   // 50000
  const int E = in_sizes[1] / 2;     // 800000
  const int* srcp = ei;
  const int* dstp = ei + E;

  char* ws = (char*)d_ws;
  size_t off = 0;
  auto alloc = [&](size_t nbytes) {
    char* p = ws + off;
    off += (nbytes + 255) & ~(size_t)255;
    return p;
  };
  unsigned char* h1q = (unsigned char*)alloc((size_t)N * 256);
  float* hscale = (float*)alloc((size_t)N * 4);
  half8* Bpack = (half8*)alloc((size_t)4096 * 16);
  float* a1s = (float*)alloc((size_t)N * 4 * 4);
  float* a1d = (float*)alloc((size_t)N * 4 * 4);
  __half* h2 = (__half*)alloc((size_t)N * 16 * 2);
  float* a2sv = (float*)alloc((size_t)N * 4);
  float* a2dv = (float*)alloc((size_t)N * 4);
  int* deg = (int*)alloc((size_t)N * 4);
  int* excl = (int*)alloc((size_t)N * 4);
  int* bsum = (int*)alloc(256 * 4);
  int* rowptr = (int*)alloc((size_t)(N + 1) * 4);
  int* rank = (int*)alloc((size_t)E * 4);
  int* elist = (int*)alloc((size_t)(E + (size_t)N) * 4);

  const int nb = (N + 255) / 256;          // 196
  const int gemmBlocks = (N / 16 + 3) / 4; // 782
  const int histBlocks = 512;

  // L1: pack W1 + zero deg
  prep1<<<16 + nb, 256, 0, stream>>>(W1, Bpack, deg, N);
  // L2: gemm1 (MFMA -> int8 + scales, fused att dots) || hist+rank
  phase2<<<gemmBlocks + histBlocks, 256, 0, stream>>>(
      x, Bpack, as1, ad1, h1q, hscale, a1s, a1d, dstp, deg, rank, N, E,
      gemmBlocks, histBlocks);
  // CSR: scan, rowptr + self-loops, atomic-free scatter
  scan_local<<<nb, 256, 0, stream>>>(deg, excl, bsum, N);
  scan_add2<<<nb, 256, 0, stream>>>(excl, bsum, rowptr, elist, N, nb);
  scatter2<<<(E + 255) / 256, 256, 0, stream>>>(srcp, dstp, rank, rowptr, elist, E);
  // layer 1 aggregate (+ fused GEMM2 / att2): 2 nodes per wave, 8 per block
  agg1_fused<<<(N + 7) / 8, 256, 0, stream>>>(rowptr, elist, h1q, hscale, a1s, a1d,
                                              b1, W2, as2, ad2, h2, a2sv, a2dv, N);
  // layer 2 aggregate
  agg2_csr<<<(N + 3) / 4, 256, 0, stream>>>(rowptr, elist, h2, a2sv, a2dv, b2, out, N);
}

// Round 2
// 249.756 us; speedup vs baseline: 1.0376x; 1.0376x over previous
//
#include <hip/hip_runtime.h>
#include <hip/hip_fp16.h>
#include <math.h>

#define NEG_SLOPE 0.2f
#define LOG2E 1.44269504088896f

#if __has_builtin(__builtin_amdgcn_exp2f)
#define EXP2(x) __builtin_amdgcn_exp2f(x)
#else
#define EXP2(x) exp2f(x)
#endif

typedef _Float16 half8 __attribute__((ext_vector_type(8)));
typedef float floatx4 __attribute__((ext_vector_type(4)));

// ---------------- L1: pack W1 (blocks 0..15) + zero deg (blocks 16..) --------------
__global__ __launch_bounds__(256) void prep1(const float* __restrict__ W1,
                                             half8* __restrict__ Bpack,
                                             int* __restrict__ deg, int N) {
  if (blockIdx.x < 16) {
    int tid = blockIdx.x * 256 + threadIdx.x;  // 4096 total
    int l = tid & 63;
    int ksnt = tid >> 6;
    int ks = ksnt & 3;
    int nt = ksnt >> 2;
    int col = nt * 16 + (l & 15);
    int krow = ks * 32 + (l >> 4) * 8;
    half8 v;
#pragma unroll
    for (int j = 0; j < 8; j++) v[j] = (_Float16)W1[(krow + j) * 256 + col];
    Bpack[tid] = v;
  } else {
    int i = (blockIdx.x - 16) * 256 + threadIdx.x;
    if (i < N) deg[i] = 0;
  }
}

// ---------------- L2: gemm1 MFMA -> int8 h1 (per-row scale) + att dots ∥ hist+rank --
// a1sx layout: per node, 8 floats (32B, line-merged): [0..3]=a1s*log2e, [4]=hscale.
__global__ __launch_bounds__(256) void phase2(
    const float* __restrict__ x, const half8* __restrict__ Bpack,
    const float* __restrict__ att_s, const float* __restrict__ att_d,
    unsigned char* __restrict__ h1q, float* __restrict__ a1sx,
    float* __restrict__ a1d,
    const int* __restrict__ dst, int* __restrict__ deg, int* __restrict__ rank,
    int N, int E, int gemmBlocks, int histBlocks) {
  if ((int)blockIdx.x >= gemmBlocks) {
    int b = blockIdx.x - gemmBlocks;
    for (int e = b * 256 + threadIdx.x; e < E; e += histBlocks * 256)
      rank[e] = atomicAdd(deg + dst[e], 1);
    return;
  }
  const int wave = threadIdx.x >> 6, lane = threadIdx.x & 63;
  const int quad = lane >> 4, li = lane & 15;
  const int n0 = (blockIdx.x * 4 + wave) * 16;
  if (n0 >= N) return;
  floatx4 acc[16];
#pragma unroll
  for (int t = 0; t < 16; t++) acc[t] = (floatx4){0.f, 0.f, 0.f, 0.f};
  const float* xrow = x + (size_t)(n0 + li) * 128;
#pragma unroll
  for (int ks = 0; ks < 4; ks++) {
    float4 xa = *(const float4*)(xrow + ks * 32 + quad * 8);
    float4 xb = *(const float4*)(xrow + ks * 32 + quad * 8 + 4);
    half8 a;
    a[0] = (_Float16)xa.x; a[1] = (_Float16)xa.y;
    a[2] = (_Float16)xa.z; a[3] = (_Float16)xa.w;
    a[4] = (_Float16)xb.x; a[5] = (_Float16)xb.y;
    a[6] = (_Float16)xb.z; a[7] = (_Float16)xb.w;
#pragma unroll
    for (int nt = 0; nt < 16; nt++) {
      half8 b = Bpack[(nt * 4 + ks) * 64 + lane];
      acc[nt] = __builtin_amdgcn_mfma_f32_16x16x32_f16(a, b, acc[nt], 0, 0, 0);
    }
  }
  // int8 quantize: row (m = quad*4 + r) absmax over 256 ch -> scale
#pragma unroll
  for (int r = 0; r < 4; r++) {
    float m = 0.f;
#pragma unroll
    for (int nt = 0; nt < 16; nt++) m = fmaxf(m, fabsf(acc[nt][r]));
#pragma unroll
    for (int off = 8; off > 0; off >>= 1) m = fmaxf(m, __shfl_xor(m, off, 16));
    m = fmaxf(m, 1e-8f);
    float inv = 127.0f / m;
    int node = n0 + quad * 4 + r;
    if (li == 0) a1sx[(size_t)node * 8 + 4] = m * (1.0f / 127.0f);
#pragma unroll
    for (int nt = 0; nt < 16; nt++) {
      h1q[(size_t)node * 256 + nt * 16 + li] =
          (unsigned char)(int)(fmaf(acc[nt][r], inv, 128.5f));
    }
  }
  // fused attention dots (fp32 acc, pre-quantization), pre-scaled by log2e
  float as_f[16], ad_f[16];
#pragma unroll
  for (int nt = 0; nt < 16; nt++) {
    as_f[nt] = att_s[nt * 16 + li];
    ad_f[nt] = att_d[nt * 16 + li];
  }
#pragma unroll
  for (int r = 0; r < 4; r++) {
    int node = n0 + quad * 4 + r;
#pragma unroll
    for (int h = 0; h < 4; h++) {
      float vs = 0.f, vd = 0.f;
#pragma unroll
      for (int ntl = 0; ntl < 4; ntl++) {
        int nt = h * 4 + ntl;
        vs = fmaf(acc[nt][r], as_f[nt], vs);
        vd = fmaf(acc[nt][r], ad_f[nt], vd);
      }
#pragma unroll
      for (int off = 8; off > 0; off >>= 1) {
        vs += __shfl_down(vs, off, 16);
        vd += __shfl_down(vd, off, 16);
      }
      if (li == 0) {
        a1sx[(size_t)node * 8 + h] = vs * LOG2E;
        a1d[node * 4 + h] = vd * LOG2E;
      }
    }
  }
}

// ---------------- CSR scan chain (unpadded rows) ----------------
__global__ void scan_local(const int* __restrict__ deg, int* __restrict__ excl,
                           int* __restrict__ bsum, int N) {
  __shared__ int s[256];
  int i = blockIdx.x * 256 + threadIdx.x;
  int v = (i < N) ? deg[i] + 1 : 0;  // +1 self-loop
  s[threadIdx.x] = v;
  __syncthreads();
  for (int off = 1; off < 256; off <<= 1) {
    int t = (threadIdx.x >= off) ? s[threadIdx.x - off] : 0;
    __syncthreads();
    s[threadIdx.x] += t;
    __syncthreads();
  }
  if (i < N) excl[i] = s[threadIdx.x] - v;
  if (threadIdx.x == 255) bsum[blockIdx.x] = s[255];
}

// scan_add2: every block re-scans bsum in LDS (nb <= 256), writes rowptr + self-loop
__global__ void scan_add2(const int* __restrict__ excl, const int* __restrict__ bsum,
                          int* __restrict__ rowptr, int* __restrict__ elist,
                          int N, int nb) {
  __shared__ int s[256];
  int v = (threadIdx.x < nb) ? bsum[threadIdx.x] : 0;
  s[threadIdx.x] = v;
  __syncthreads();
  for (int off = 1; off < 256; off <<= 1) {
    int t = (threadIdx.x >= off) ? s[threadIdx.x - off] : 0;
    __syncthreads();
    s[threadIdx.x] += t;
    __syncthreads();
  }
  __syncthreads();
  int base = (blockIdx.x > 0) ? s[blockIdx.x - 1] : 0;  // exclusive block offset
  int i = blockIdx.x * 256 + threadIdx.x;
  if (i < N) {
    int r = excl[i] + base;
    rowptr[i] = r;
    elist[r] = i;  // self-loop first
  }
  if (blockIdx.x == 0 && threadIdx.x == 0) rowptr[N] = s[nb - 1];  // total = ET
}

// ---------------- atomic-free scatter via precomputed rank ----------------
__global__ void scatter2(const int* __restrict__ src, const int* __restrict__ dst,
                         const int* __restrict__ rank, const int* __restrict__ rowptr,
                         int* __restrict__ elist, int E) {
  int e = blockIdx.x * 256 + threadIdx.x;
  if (e >= E) return;
  elist[rowptr[dst[e]] + 1 + rank[e]] = src[e];
}

// ---------------- agg1: R0 structure (2 nodes/wave, half-wave = 1 node, 32 lanes
// x 8 int8 channels). Layout change vs R0: a1s+hscale merged into one stride-8
// float row (32B-aligned) -> the two per-edge metadata gathers share one 64B line.
// Epilogue writes a2s/a2d into the h2 row tail (bytes 20-27) so agg2 reads ONE
// line per edge. ------------------------------------------------------------------
__global__ __launch_bounds__(256) void agg1_fused(
    const int* __restrict__ rowptr, const int* __restrict__ elist,
    const unsigned char* __restrict__ h1q, const float* __restrict__ a1sx,
    const float* __restrict__ a1d,
    const float* __restrict__ b1, const float* __restrict__ W2,
    const float* __restrict__ as2, const float* __restrict__ ad2,
    __half* __restrict__ h2, int N) {
  __shared__ float w2s[64 * 41];   // lane-stride 41 -> conflict-free
  __shared__ float cbuf[8][256];   // normalized pre-bias outputs of this block's nodes
  const int t = threadIdx.x;
  for (int i = t; i < 2560; i += 256) {
    int ch = i / 10, jj = i - ch * 10;
    w2s[(ch >> 2) * 41 + (ch & 3) * 10 + jj] = W2[i];
  }

  const int wave = t >> 6, lane = t & 63;
  const int half = lane >> 5, l32 = lane & 31;
  const int slot = wave * 2 + half;        // node slot in block: 0..7
  const int n = blockIdx.x * 8 + slot;
  const bool act = n < N;
  const int row = act ? rowptr[n] : 0;
  const int deg = act ? rowptr[n + 1] - row : 0;
  const int* el = elist + row;
  const int hidx = l32 >> 3;               // head of this lane's 8 channels
  const float adh = act ? a1d[n * 4 + hidx] : 0.f;  // pre-scaled by log2e

  float den = 0.f, T = 0.f;
  float acc[8];
#pragma unroll
  for (int k = 0; k < 8; k++) acc[k] = 0.f;

  int j = 0;
  for (; j + 4 <= deg; j += 4) {
    int ss[4];
    float lv[4], sc[4];
    uint2 qv[4];
#pragma unroll
    for (int u = 0; u < 4; u++) ss[u] = el[j + u];
#pragma unroll
    for (int u = 0; u < 4; u++) {
      const float* mp = a1sx + (size_t)ss[u] * 8;
      lv[u] = mp[hidx];
      sc[u] = mp[4];
      qv[u] = *(const uint2*)(h1q + (size_t)ss[u] * 256 + l32 * 8);
    }
#pragma unroll
    for (int u = 0; u < 4; u++) {
      float l = lv[u] + adh;
      float e = EXP2(fmaxf(l, NEG_SLOPE * l));
      den += e;
      float se = e * sc[u];
      T += se;
      unsigned int a = qv[u].x, b = qv[u].y;
      acc[0] = fmaf((float)(a & 0xffu), se, acc[0]);
      acc[1] = fmaf((float)((a >> 8) & 0xffu), se, acc[1]);
      acc[2] = fmaf((float)((a >> 16) & 0xffu), se, acc[2]);
      acc[3] = fmaf((float)(a >> 24), se, acc[3]);
      acc[4] = fmaf((float)(b & 0xffu), se, acc[4]);
      acc[5] = fmaf((float)((b >> 8) & 0xffu), se, acc[5]);
      acc[6] = fmaf((float)((b >> 16) & 0xffu), se, acc[6]);
      acc[7] = fmaf((float)(b >> 24), se, acc[7]);
    }
  }
  for (; j < deg; j++) {
    int s0 = el[j];
    const float* mp = a1sx + (size_t)s0 * 8;
    float l0 = mp[hidx] + adh;
    float sc0 = mp[4];
    uint2 q0 = *(const uint2*)(h1q + (size_t)s0 * 256 + l32 * 8);
    float e0 = EXP2(fmaxf(l0, NEG_SLOPE * l0));
    den += e0;
    float se = e0 * sc0;
    T += se;
    unsigned int a = q0.x, b = q0.y;
    acc[0] = fmaf((float)(a & 0xffu), se, acc[0]);
    acc[1] = fmaf((float)((a >> 8) & 0xffu), se, acc[1]);
    acc[2] = fmaf((float)((a >> 16) & 0xffu), se, acc[2]);
    acc[3] = fmaf((float)(a >> 24), se, acc[3]);
    acc[4] = fmaf((float)(b & 0xffu), se, acc[4]);
    acc[5] = fmaf((float)((b >> 8) & 0xffu), se, acc[5]);
    acc[6] = fmaf((float)((b >> 16) & 0xffu), se, acc[6]);
    acc[7] = fmaf((float)(b >> 24), se, acc[7]);
  }

  // normalized, offset-corrected, pre-bias values -> LDS
  if (act) {
    float inv = 1.0f / den;
    float corr = 128.0f * T;
    float4 v0 = make_float4((acc[0] - corr) * inv, (acc[1] - corr) * inv,
                            (acc[2] - corr) * inv, (acc[3] - corr) * inv);
    float4 v1 = make_float4((acc[4] - corr) * inv, (acc[5] - corr) * inv,
                            (acc[6] - corr) * inv, (acc[7] - corr) * inv);
    *(float4*)&cbuf[slot][l32 * 8] = v0;
    *(float4*)&cbuf[slot][l32 * 8 + 4] = v1;
  }
  __syncthreads();

  // epilogue (R10 layout): wave handles its 2 nodes sequentially, 4 ch/lane
  float4 bb = *(const float4*)(b1 + lane * 4);
  const float* w0 = w2s + lane * 41;
#pragma unroll
  for (int pp = 0; pp < 2; pp++) {
    int slot2 = wave * 2 + pp;
    int n2 = blockIdx.x * 8 + slot2;
    if (n2 >= N) continue;  // uniform per wave
    float4 cv = *(const float4*)&cbuf[slot2][lane * 4];
    float c0 = cv.x + bb.x;
    float c1 = cv.y + bb.y;
    float c2 = cv.z + bb.z;
    float c3 = cv.w + bb.w;
    c0 = c0 > 0.f ? c0 : expm1f(c0);
    c1 = c1 > 0.f ? c1 : expm1f(c1);
    c2 = c2 > 0.f ? c2 : expm1f(c2);
    c3 = c3 > 0.f ? c3 : expm1f(c3);
    float p[10];
#pragma unroll
    for (int jj = 0; jj < 10; jj++)
      p[jj] = fmaf(c0, w0[jj],
              fmaf(c1, w0[10 + jj], fmaf(c2, w0[20 + jj], c3 * w0[30 + jj])));
#pragma unroll
    for (int jj = 0; jj < 10; jj++) {
#pragma unroll
      for (int off = 32; off > 0; off >>= 1) p[jj] += __shfl_down(p[jj], off, 64);
    }
    if (lane == 0) {
      float ds = 0.f, dd = 0.f;
#pragma unroll
      for (int jj = 0; jj < 10; jj++) {
        h2[(size_t)n2 * 16 + jj] = __float2half(p[jj]);
        ds = fmaf(p[jj], as2[jj], ds);
        dd = fmaf(p[jj], ad2[jj], dd);
      }
      // embed att2 dots in the unused tail of the 32B h2 row (bytes 20-27):
      float* ft = (float*)(h2 + (size_t)n2 * 16);
      ft[5] = ds * LOG2E;   // a2s
      ft[6] = dd * LOG2E;   // a2d
    }
  }
}

// ---------------- agg2: wave-per-node, 12 groups x 5 lanes (half2 = 2 channels).
// a2s/a2d read from the h2 row tail -> exactly ONE 64B line per edge. -------------
__global__ __launch_bounds__(256) void agg2_csr(
    const int* __restrict__ rowptr, const int* __restrict__ elist,
    const __half* __restrict__ h2, const float* __restrict__ b2,
    float* __restrict__ out, int N) {
  int wave = threadIdx.x >> 6, lane = threadIdx.x & 63;
  int n = blockIdx.x * 4 + wave;
  if (n >= N) return;
  int row = rowptr[n];
  int deg = rowptr[n + 1] - row;
  const int* el = elist + row;
  const float* hf = (const float*)h2;
  float ad = hf[(size_t)n * 8 + 6];  // pre-scaled a2d from own row tail
  int g = lane / 5;      // 0..11 active, lanes 60-63 idle (g=12)
  int c2 = lane - g * 5; // channel-pair index 0..4
  float den = 0.f, ax = 0.f, ay = 0.f;
  if (g < 12) {
    int jj = g;
    for (; jj + 12 < deg; jj += 24) {
      int sA = el[jj], sB = el[jj + 12];
      float lA = hf[(size_t)sA * 8 + 5] + ad;
      float lB = hf[(size_t)sB * 8 + 5] + ad;
      __half2 hA = *(const __half2*)(h2 + (size_t)sA * 16 + c2 * 2);
      __half2 hB = *(const __half2*)(h2 + (size_t)sB * 16 + c2 * 2);
      float eA = EXP2(fmaxf(lA, NEG_SLOPE * lA));
      float eB = EXP2(fmaxf(lB, NEG_SLOPE * lB));
      den += eA + eB;
      float2 fA = __half22float2(hA);
      float2 fB = __half22float2(hB);
      ax = fmaf(eA, fA.x, fmaf(eB, fB.x, ax));
      ay = fmaf(eA, fA.y, fmaf(eB, fB.y, ay));
    }
    for (; jj < deg; jj += 12) {
      int s = el[jj];
      float l = hf[(size_t)s * 8 + 5] + ad;
      __half2 hv = *(const __half2*)(h2 + (size_t)s * 16 + c2 * 2);
      float ev = EXP2(fmaxf(l, NEG_SLOPE * l));
      den += ev;
      float2 f = __half22float2(hv);
      ax = fmaf(ev, f.x, ax);
      ay = fmaf(ev, f.y, ay);
    }
  }
  // reduce the 12 stride-5 groups: +30 (g+6), then +10/+20 (g+2,g+4), then +5 (g+1)
  ax += __shfl_down(ax, 30, 64);
  ay += __shfl_down(ay, 30, 64);
  den += __shfl_down(den, 30, 64);
  ax += __shfl_down(ax, 10, 64) + __shfl_down(ax, 20, 64);
  ay += __shfl_down(ay, 10, 64) + __shfl_down(ay, 20, 64);
  den += __shfl_down(den, 10, 64) + __shfl_down(den, 20, 64);
  ax += __shfl_down(ax, 5, 64);
  ay += __shfl_down(ay, 5, 64);
  den += __shfl_down(den, 5, 64);
  if (lane < 5) {
    float inv = 1.0f / den;
    float2 bb = *(const float2*)(b2 + lane * 2);
    float2 o = make_float2(fmaf(ax, inv, bb.x), fmaf(ay, inv, bb.y));
    *(float2*)(out + (size_t)n * 10 + lane * 2) = o;
  }
}

extern "C" void kernel_launch(void* const* d_in, const int* in_sizes, int n_in,
                              void* d_out, int out_size, void* d_ws, size_t ws_size,
                              hipStream_t stream) {
  const float* x = (const float*)d_in[0];
  const int* ei = (const int*)d_in[1];
  const float* W1 = (const float*)d_in[2];
  const float* as1 = (const float*)d_in[3];
  const float* ad1 = (const float*)d_in[4];
  const float* b1 = (const float*)d_in[5];
  const float* W2 = (const float*)d_in[6];
  const float* as2 = (const float*)d_in[7];
  const float* ad2 = (const float*)d_in[8];
  const float* b2 = (const float*)d_in[9];
  float* out = (float*)d_out;

  const int N = in_sizes[0] / 128;   // 50000
  const int E = in_sizes[1] / 2;     // 800000
  const int* srcp = ei;
  const int* dstp = ei + E;

  char* ws = (char*)d_ws;
  size_t off = 0;
  auto alloc = [&](size_t nbytes) {
    char* p = ws + off;
    off += (nbytes + 255) & ~(size_t)255;
    return p;
  };
  unsigned char* h1q = (unsigned char*)alloc((size_t)N * 256);
  float* a1sx = (float*)alloc((size_t)N * 8 * 4);   // [a1s*4, hscale, pad*3]
  half8* Bpack = (half8*)alloc((size_t)4096 * 16);
  float* a1d = (float*)alloc((size_t)N * 4 * 4);
  __half* h2 = (__half*)alloc((size_t)N * 16 * 2);  // 10 half + a2s/a2d floats in tail
  int* deg = (int*)alloc((size_t)N * 4);
  int* excl = (int*)alloc((size_t)N * 4);
  int* bsum = (int*)alloc(256 * 4);
  int* rowptr = (int*)alloc((size_t)(N + 1) * 4);
  int* rank = (int*)alloc((size_t)E * 4);
  int* elist = (int*)alloc((size_t)(E + (size_t)N) * 4);

  const int nb = (N + 255) / 256;          // 196
  const int gemmBlocks = (N / 16 + 3) / 4; // 782
  const int histBlocks = 512;

  // L1: pack W1 + zero deg
  prep1<<<16 + nb, 256, 0, stream>>>(W1, Bpack, deg, N);
  // L2: gemm1 (MFMA -> int8 + scales, fused att dots) || hist+rank
  phase2<<<gemmBlocks + histBlocks, 256, 0, stream>>>(
      x, Bpack, as1, ad1, h1q, a1sx, a1d, dstp, deg, rank, N, E,
      gemmBlocks, histBlocks);
  // CSR: scan, rowptr + self-loops, atomic-free scatter
  scan_local<<<nb, 256, 0, stream>>>(deg, excl, bsum, N);
  scan_add2<<<nb, 256, 0, stream>>>(excl, bsum, rowptr, elist, N, nb);
  scatter2<<<(E + 255) / 256, 256, 0, stream>>>(srcp, dstp, rank, rowptr, elist, E);
  // layer 1 aggregate (+ fused GEMM2 / att2): 2 nodes per wave, 8 per block
  agg1_fused<<<(N + 7) / 8, 256, 0, stream>>>(rowptr, elist, h1q, a1sx, a1d,
                                              b1, W2, as2, ad2, h2, N);
  // layer 2 aggregate
  agg2_csr<<<(N + 3) / 4, 256, 0, stream>>>(rowptr, elist, h2, b2, out, N);
}